// Round 12
// baseline (310.306 us; speedup 1.0000x reference)
//
#include <hip/hip_runtime.h>
#include <hip/hip_bf16.h>
#include <math.h>

typedef __bf16 bf16x8 __attribute__((ext_vector_type(8)));
typedef float f32x4 __attribute__((ext_vector_type(4)));
typedef float f32x16 __attribute__((ext_vector_type(16)));
typedef unsigned short u16x4 __attribute__((ext_vector_type(4)));

#define AS1P const __attribute__((address_space(1))) void*
#define AS3P __attribute__((address_space(3))) void*

__device__ __forceinline__ float b2f(unsigned short h) {
    unsigned int u = ((unsigned int)h) << 16;
    return __builtin_bit_cast(float, u);
}
__device__ __forceinline__ unsigned short f2b(float f) {
    unsigned int u = __builtin_bit_cast(unsigned int, f);
    u += 0x7FFFu + ((u >> 16) & 1u);
    return (unsigned short)(u >> 16);
}
__device__ __forceinline__ float silu(float c) {
    return c * __builtin_amdgcn_rcpf(1.0f + __expf(-c));
}

// ---------------- tiled transpose + bf16 convert
__global__ __launch_bounds__(256) void k_convT(const float* __restrict__ src,
                                               unsigned short* __restrict__ dst,
                                               int R, int C) {
    __shared__ float tile[32][33];
    int tx = threadIdx.x, ty = threadIdx.y;
    int r0 = blockIdx.y << 5, c0 = blockIdx.x << 5;
#pragma unroll
    for (int i = 0; i < 4; ++i)
        tile[ty + 8 * i][tx] = src[(long long)(r0 + ty + 8 * i) * C + c0 + tx];
    __syncthreads();
#pragma unroll
    for (int i = 0; i < 4; ++i)
        dst[(long long)(c0 + ty + 8 * i) * R + r0 + tx] = f2b(tile[tx][ty + 8 * i]);
}

// ---------------- LayerNorm
__global__ __launch_bounds__(256) void k_ln(const float* __restrict__ x,
                                            const float* __restrict__ g,
                                            const float* __restrict__ b,
                                            unsigned short* __restrict__ xn) {
    int row = blockIdx.x;
    int t = threadIdx.x;
    const float* xr = x + (long long)row * 768;
    float v0 = xr[t], v1 = xr[t + 256], v2 = xr[t + 512];
    float s = v0 + v1 + v2;
    float q = v0 * v0 + v1 * v1 + v2 * v2;
#pragma unroll
    for (int off = 32; off > 0; off >>= 1) {
        s += __shfl_xor(s, off);
        q += __shfl_xor(q, off);
    }
    __shared__ float ss[4], sq[4];
    int w = t >> 6;
    if ((t & 63) == 0) { ss[w] = s; sq[w] = q; }
    __syncthreads();
    float S_ = ss[0] + ss[1] + ss[2] + ss[3];
    float Q_ = sq[0] + sq[1] + sq[2] + sq[3];
    float mu = S_ * (1.0f / 768.0f);
    float var = Q_ * (1.0f / 768.0f) - mu * mu;
    float rs = rsqrtf(var + 1e-5f);
    unsigned short* xo = xn + (long long)row * 768;
    xo[t]       = f2b((v0 - mu) * rs * g[t]       + b[t]);
    xo[t + 256] = f2b((v1 - mu) * rs * g[t + 256] + b[t + 256]);
    xo[t + 512] = f2b((v2 - mu) * rs * g[t + 512] + b[t + 512]);
}

// ---------------- RoPE + per-head affine
__global__ __launch_bounds__(128) void k_rope(const unsigned short* __restrict__ bS,
                                              const float* __restrict__ gqk,
                                              const float* __restrict__ bqk,
                                              unsigned short* __restrict__ q,
                                              unsigned short* __restrict__ k) {
    int row = blockIdx.x;
    int l = row & 511;
    int s = threadIdx.x;
    int j = s & 63;
    int partner = s ^ 64;
    float b0 = b2f(bS[(long long)row * 128 + s]);
    float bp = b2f(bS[(long long)row * 128 + partner]);
    float invf = __expf((float)j * -0.14391156831f);
    float th = (float)l * invf;
    float sn, cs;
    __sincosf(th, &sn, &cs);
    float sign = (s < 64) ? -1.0f : 1.0f;
    float preq  = b0 * gqk[s]           + bqk[s];
    float preqp = bp * gqk[partner]     + bqk[partner];
    q[(long long)row * 128 + s] = f2b(preq * cs + sign * preqp * sn);
    float prek  = b0 * gqk[128 + s]       + bqk[128 + s];
    float prekp = bp * gqk[128 + partner] + bqk[128 + partner];
    k[(long long)row * 128 + s] = f2b(prek * cs + sign * prekp * sn);
}

// ================= 128^2 2-phase kernel (QK only: P = relu^2(qk/L + bias))
__global__ __launch_bounds__(256) void k_qk(const unsigned short* __restrict__ A,
                                            const unsigned short* __restrict__ B,
                                            const float* __restrict__ wrel,
                                            unsigned short* __restrict__ P) {
    __shared__ __align__(16) unsigned short As[128 * 64];
    __shared__ __align__(16) unsigned short Bs[128 * 64];
    int t = threadIdx.x;
    int w = t >> 6, lane = t & 63;
    int wr = w >> 1, wc = w & 1;
    int bx = blockIdx.x, by = blockIdx.y, bz = blockIdx.z;
    {   // flat xyz swizzle (512 blocks, %8==0 -> bijective)
        int gx = gridDim.x, gy = gridDim.y;
        int nb = gx * gy * gridDim.z;
        int bid = (bz * gy + by) * gx + bx;
        int s = (bid & 7) * (nb >> 3) + (bid >> 3);
        bx = s % gx;
        by = (s / gx) % gy;
        bz = s / (gx * gy);
    }
    const unsigned short* Ab = A + (long long)bz * 512 * 128 + (long long)by * 128 * 128;
    const unsigned short* Bb = B + (long long)bz * 512 * 128 + (long long)bx * 128 * 128;

    f32x4 acc[4][4];
#pragma unroll
    for (int m = 0; m < 4; ++m)
#pragma unroll
        for (int n = 0; n < 4; ++n) acc[m][n] = (f32x4){0.f, 0.f, 0.f, 0.f};

    int rowA = (w << 3) + (lane >> 3);
    int colA = (lane & 7) << 3;

    for (int k0 = 0; k0 < 128; k0 += 64) {
#pragma unroll
        for (int i = 0; i < 4; ++i) {
            int r = (i << 5) + rowA;
            __builtin_amdgcn_global_load_lds(
                (AS1P)(Ab + (long long)r * 128 + k0 + colA),
                (AS3P)(&As[(i << 11) + (w << 9)]), 16, 0, 0);
            __builtin_amdgcn_global_load_lds(
                (AS1P)(Bb + (long long)r * 128 + k0 + colA),
                (AS3P)(&Bs[(i << 11) + (w << 9)]), 16, 0, 0);
        }
        __syncthreads();
#pragma unroll
        for (int ks = 0; ks < 2; ++ks) {
            bf16x8 af[4], bfr[4];
#pragma unroll
            for (int m = 0; m < 4; ++m)
                af[m] = *(const bf16x8*)&As[((wr << 6) + (m << 4) + (lane & 15)) * 64 +
                                            (ks << 5) + ((lane >> 4) << 3)];
#pragma unroll
            for (int n = 0; n < 4; ++n)
                bfr[n] = *(const bf16x8*)&Bs[((wc << 6) + (n << 4) + (lane & 15)) * 64 +
                                             (ks << 5) + ((lane >> 4) << 3)];
#pragma unroll
            for (int m = 0; m < 4; ++m)
#pragma unroll
                for (int n = 0; n < 4; ++n)
                    acc[m][n] = __builtin_amdgcn_mfma_f32_16x16x32_bf16(bfr[n], af[m],
                                                                        acc[m][n], 0, 0, 0);
        }
        __syncthreads();
    }

    int c15 = lane & 15, qq = lane >> 4;
    int rowb = (by << 7) + (wr << 6) + c15;
    int colb = (bx << 7) + (wc << 6) + (qq << 2);
#pragma unroll
    for (int m = 0; m < 4; ++m) {
#pragma unroll
        for (int n = 0; n < 4; ++n) {
            int grow = rowb + (m << 4);
            int gcol = colb + (n << 4);
            f32x4 a = acc[m][n];
            int base = gcol - grow + 511;
            u16x4 o;
#pragma unroll
            for (int i = 0; i < 4; ++i) {
                float val = a[i] * (1.0f / 512.0f) + wrel[base + i];
                val = fmaxf(val, 0.0f);
                o[i] = f2b(val * val);
            }
            *(u16x4*)(P + ((long long)(bz * 512 + grow)) * 512 + gcol) = o;
        }
    }
}

// ================= 256x256 8-phase kernel, 32x32x16 MFMA variant.
// Same R7-verified sync ledger (stage order, vmcnt(8)@ph1/ph3, barriers, swizzle);
// fragments are 32x32: per wave 4x2 frags of 32^2 (acc 128 VGPR), 32 MFMA/K-tile.
// A/B frag read: row = base + (lane&31), k-slice = ksl*16 + (lane>>5)*8 (one b128).
__device__ __forceinline__ bf16x8 ldsread(const unsigned short* p) {
    bf16x8 r;
    unsigned int off =
        (unsigned int)(unsigned long long)(__attribute__((address_space(3))) const void*)p;
    asm volatile("ds_read_b128 %0, %1" : "=v"(r) : "v"(off));
    return r;
}
// stage one half-tile: 256 rows x 32 cols (16KB), 512 threads x 2 loads.
__device__ __forceinline__ void stage_half(const unsigned short* __restrict__ g, int ldk,
                                           unsigned short* lds, int t) {
#pragma unroll
    for (int i = 0; i < 2; ++i) {
        int slot = t + (i << 9);
        int row = slot >> 2;
        int gs = (slot & 3) ^ ((slot >> 3) & 3);
        __builtin_amdgcn_global_load_lds(
            (AS1P)(g + (long long)row * ldk + (gs << 3)),
            (AS3P)(lds + slot * 8), 16, 0, 0);
    }
}

template <bool SWAP, int NT>
__device__ __forceinline__ void kloop8(const unsigned short* __restrict__ Ab,
                                       const unsigned short* __restrict__ Bb,
                                       unsigned short* As, unsigned short* Bs,
                                       f32x16 (&acc)[4][2], int tid,
                                       int wr, int wc, int l31, int hi, int s3) {
    constexpr int K = NT * 64;
    // prologue: tile0 all 4 halves + tile1 K0 halves
    stage_half(Ab, K, As + 0, tid);
    stage_half(Bb, K, Bs + 0, tid);
    stage_half(Ab + 32, K, As + 8192, tid);
    stage_half(Bb + 32, K, Bs + 8192, tid);
    stage_half(Ab + 64, K, As + 16384, tid);
    stage_half(Bb + 64, K, Bs + 16384, tid);
    asm volatile("s_waitcnt vmcnt(8)" ::: "memory");
    __builtin_amdgcn_s_barrier();

    // per-thread swizzled granule index for ksl 0/1 (shorts offset = g*8)
    const int gk0 = (hi ^ s3) << 3;
    const int gk1 = ((2 | hi) ^ s3) << 3;

    bf16x8 bfr[4], af[4];
    for (int t = 0; t < NT; ++t) {
        const int b = t & 1;
        const unsigned short* A0 = As + b * 16384;
        const unsigned short* B0 = Bs + b * 16384;
#pragma unroll
        for (int p = 0; p < 4; ++p) {
            const int ks = p >> 1, mh = p & 1;
            const unsigned short* At = A0 + ks * 8192;
            const unsigned short* Bt = B0 + ks * 8192;
            if (mh == 0) {
#pragma unroll
                for (int n = 0; n < 2; ++n) {
                    bfr[n * 2 + 0] = ldsread(Bt + (wc * 64 + n * 32 + l31) * 32 + gk0);
                    bfr[n * 2 + 1] = ldsread(Bt + (wc * 64 + n * 32 + l31) * 32 + gk1);
                }
            }
#pragma unroll
            for (int j = 0; j < 2; ++j) {
                af[j * 2 + 0] = ldsread(At + (wr * 128 + mh * 64 + j * 32 + l31) * 32 + gk0);
                af[j * 2 + 1] = ldsread(At + (wr * 128 + mh * 64 + j * 32 + l31) * 32 + gk1);
            }
            if (p == 0) {
                if (t + 1 < NT)
                    stage_half(Ab + (t + 1) * 64 + 32, K,
                               As + (((t + 1) & 1) * 2 + 1) * 8192, tid);
            } else if (p == 1) {
                if (t + 1 < NT)
                    stage_half(Bb + (t + 1) * 64 + 32, K,
                               Bs + (((t + 1) & 1) * 2 + 1) * 8192, tid);
            } else if (p == 2) {
                if (t + 2 < NT)
                    stage_half(Ab + (t + 2) * 64, K, As + (b * 2) * 8192, tid);
            } else {
                if (t + 2 < NT)
                    stage_half(Bb + (t + 2) * 64, K, Bs + (b * 2) * 8192, tid);
            }
            __builtin_amdgcn_s_barrier();
            asm volatile("s_waitcnt lgkmcnt(0)" ::: "memory");
            __builtin_amdgcn_sched_barrier(0);
            __builtin_amdgcn_s_setprio(1);
#pragma unroll
            for (int j = 0; j < 2; ++j)
#pragma unroll
                for (int n = 0; n < 2; ++n)
#pragma unroll
                    for (int ksl = 0; ksl < 2; ++ksl) {
                        if constexpr (SWAP)
                            acc[mh * 2 + j][n] = __builtin_amdgcn_mfma_f32_32x32x16_bf16(
                                bfr[n * 2 + ksl], af[j * 2 + ksl], acc[mh * 2 + j][n], 0, 0, 0);
                        else
                            acc[mh * 2 + j][n] = __builtin_amdgcn_mfma_f32_32x32x16_bf16(
                                af[j * 2 + ksl], bfr[n * 2 + ksl], acc[mh * 2 + j][n], 0, 0, 0);
                    }
            __builtin_amdgcn_s_setprio(0);
            if (p == 1) {
                if (t < NT - 1)
                    asm volatile("s_waitcnt vmcnt(8)" ::: "memory");
                else
                    asm volatile("s_waitcnt vmcnt(0)" ::: "memory");
            } else if (p == 3) {
                if (t < NT - 2)
                    asm volatile("s_waitcnt vmcnt(8)" ::: "memory");
                else if (t == NT - 2)
                    asm volatile("s_waitcnt vmcnt(4)" ::: "memory");
            }
            __builtin_amdgcn_sched_barrier(0);
            __builtin_amdgcn_s_barrier();
        }
    }
}

// EPI: 10 = UV merged (u | vT | bS by bx)   2 = gated(PV*u)   3 = out f32(+o_b+x)
// SWZ: 1 = xy chunked XCD swizzle, 2 = flat xyz chunked XCD swizzle
// 32x32 C/D layout (m74/m101): col=lane&31, row=(reg&3)+8*(reg>>2)+4*(lane>>5).
// SWAP => D-"col" = output row, D-"row" = output col.
template <int EPI, int SWZ, int NT>
__global__ __launch_bounds__(512, 2) void k8(const unsigned short* __restrict__ A,
                                             const unsigned short* __restrict__ B,
                                             long long strideA, long long strideB,
                                             void* p0, void* p1, void* p2,
                                             const void* p3) {
    constexpr int K = NT * 64;
    __shared__ __align__(16) unsigned short As[2][2][256 * 32];
    __shared__ __align__(16) unsigned short Bs[2][2][256 * 32];
    int tid = threadIdx.x;
    int w = tid >> 6, lane = tid & 63;
    int wr = w >> 2, wc = w & 3;
    int l31 = lane & 31, hi = lane >> 5;
    int s3 = (l31 >> 1) & 3;
    int bx = blockIdx.x, by = blockIdx.y, bz = blockIdx.z;
    if constexpr (SWZ == 1) {
        int gx = gridDim.x;
        int nb = gx * gridDim.y;
        int bid = by * gx + bx;
        int s = (bid & 7) * (nb >> 3) + (bid >> 3);
        bx = s % gx;
        by = s / gx;
    } else if constexpr (SWZ == 2) {
        int gx = gridDim.x, gy = gridDim.y;
        int nb = gx * gy * gridDim.z;
        int bid = (bz * gy + by) * gx + bx;
        int s = (bid & 7) * (nb >> 3) + (bid >> 3);
        bx = s % gx;
        by = (s / gx) % gy;
        bz = s / (gx * gy);
    }
    const unsigned short* Ab = A + bz * strideA + (long long)by * 256 * K;
    const unsigned short* Bb = B + bz * strideB + (long long)bx * 256 * K;

    f32x16 acc[4][2];
#pragma unroll
    for (int m = 0; m < 4; ++m)
#pragma unroll
        for (int n = 0; n < 2; ++n)
#pragma unroll
            for (int i = 0; i < 16; ++i) acc[m][n][i] = 0.f;

    bool swapped = true;
    if constexpr (EPI == 10) {
        swapped = !(bx >= 6 && bx < 12);
        if (swapped)
            kloop8<true, NT>(Ab, Bb, &As[0][0][0], &Bs[0][0][0], acc, tid, wr, wc, l31, hi, s3);
        else
            kloop8<false, NT>(Ab, Bb, &As[0][0][0], &Bs[0][0][0], acc, tid, wr, wc, l31, hi, s3);
    } else {
        kloop8<true, NT>(Ab, Bb, &As[0][0][0], &Bs[0][0][0], acc, tid, wr, wc, l31, hi, s3);
    }

    if constexpr (EPI == 10) {
        if (swapped) {  // u (bx<6) or bS (bx==12)
            int rowb = by * 256 + wr * 128 + l31;
            int colb = bx * 256 + wc * 64 + (hi << 2);
#pragma unroll
            for (int fm = 0; fm < 4; ++fm) {
                int R = rowb + fm * 32;
#pragma unroll
                for (int fn = 0; fn < 2; ++fn) {
#pragma unroll
                    for (int q = 0; q < 4; ++q) {
                        int C = colb + fn * 32 + q * 8;
                        u16x4 o;
                        if (C < 1536) {
                            f32x4 bb = *(const f32x4*)((const float*)p3 + C);
#pragma unroll
                            for (int i = 0; i < 4; ++i)
                                o[i] = f2b(silu(acc[fm][fn][q * 4 + i] + bb[i]));
                            *(u16x4*)((unsigned short*)p0 + (long long)R * 1536 + C) = o;
                        } else if (C < 3200) {  // bS
                            f32x4 bb = *(const f32x4*)((const float*)p3 + C);
#pragma unroll
                            for (int i = 0; i < 4; ++i)
                                o[i] = f2b(silu(acc[fm][fn][q * 4 + i] + bb[i]));
                            *(u16x4*)((unsigned short*)p2 + (long long)R * 128 + (C - 3072)) = o;
                        }
                    }
                }
            }
        } else {  // vT: non-swap layout, 4 consecutive out-rows per reg-quad
            int rowb = by * 256 + wr * 128 + (hi << 2);
            int colb = bx * 256 + wc * 64 + l31;
#pragma unroll
            for (int fm = 0; fm < 4; ++fm) {
#pragma unroll
                for (int fn = 0; fn < 2; ++fn) {
                    int C = colb + fn * 32;  // 1536..3071
                    float bias = ((const float*)p3)[C];
#pragma unroll
                    for (int q = 0; q < 4; ++q) {
                        int Rb = rowb + fm * 32 + q * 8;
                        u16x4 o;
#pragma unroll
                        for (int i = 0; i < 4; ++i)
                            o[i] = f2b(silu(acc[fm][fn][q * 4 + i] + bias));
                        int bb2 = Rb >> 9, mm = Rb & 511;
                        *(u16x4*)((unsigned short*)p1 +
                                  ((long long)bb2 * 1536 + (C - 1536)) * 512 + mm) = o;
                    }
                }
            }
        }
    } else if constexpr (EPI == 2) {
        int rowb = by * 256 + wr * 128 + l31;
        int colb = bx * 256 + wc * 64 + (hi << 2);
#pragma unroll
        for (int fm = 0; fm < 4; ++fm) {
            int R = rowb + fm * 32;
#pragma unroll
            for (int fn = 0; fn < 2; ++fn) {
#pragma unroll
                for (int q = 0; q < 4; ++q) {
                    int C = colb + fn * 32 + q * 8;
                    long long idx = ((long long)(bz * 512 + R)) * 1536 + C;
                    u16x4 uu = *(const u16x4*)((const unsigned short*)p1 + idx);
                    u16x4 o;
#pragma unroll
                    for (int i = 0; i < 4; ++i)
                        o[i] = f2b(acc[fm][fn][q * 4 + i] * b2f(uu[i]));
                    *(u16x4*)((unsigned short*)p0 + idx) = o;
                }
            }
        }
    } else {  // EPI == 3
        int rowb = by * 256 + wr * 128 + l31;
        int colb = bx * 256 + wc * 64 + (hi << 2);
#pragma unroll
        for (int fm = 0; fm < 4; ++fm) {
            int R = rowb + fm * 32;
#pragma unroll
            for (int fn = 0; fn < 2; ++fn) {
#pragma unroll
                for (int q = 0; q < 4; ++q) {
                    int C = colb + fn * 32 + q * 8;
                    long long idx = (long long)R * 768 + C;
                    f32x4 xv = *(const f32x4*)((const float*)p2 + idx);
                    f32x4 ob = *(const f32x4*)((const float*)p1 + C);
                    f32x4 o;
#pragma unroll
                    for (int i = 0; i < 4; ++i)
                        o[i] = acc[fm][fn][q * 4 + i] + ob[i] + xv[i];
                    *(f32x4*)((float*)p0 + idx) = o;
                }
            }
        }
    }
}

extern "C" void kernel_launch(void* const* d_in, const int* in_sizes, int n_in,
                              void* d_out, int out_size, void* d_ws, size_t ws_size,
                              hipStream_t stream) {
    const float* x     = (const float*)d_in[0];
    const float* ln_g  = (const float*)d_in[1];
    const float* ln_b  = (const float*)d_in[2];
    const float* uv_W  = (const float*)d_in[3];
    const float* uv_b  = (const float*)d_in[4];
    const float* g_qk  = (const float*)d_in[5];
    const float* b_qk  = (const float*)d_in[6];
    const float* w_rel = (const float*)d_in[7];
    const float* o_W   = (const float*)d_in[8];
    const float* o_b   = (const float*)d_in[9];
    float* out = (float*)d_out;

    char* ws = (char*)d_ws;
    size_t off = 0;
    auto alloc = [&](size_t bytes) {
        void* p = ws + off;
        off += (bytes + 255) & ~(size_t)255;
        return p;
    };
    unsigned short* uvWT = (unsigned short*)alloc(3328ll * 768 * 2);  // rows 3200+ = pad
    unsigned short* oWT  = (unsigned short*)alloc(768ll * 1536 * 2);
    unsigned short* xn   = (unsigned short*)alloc(16384ll * 768 * 2);
    unsigned short* u    = (unsigned short*)alloc(16384ll * 1536 * 2);
    unsigned short* vT   = (unsigned short*)alloc(32ll * 1536 * 512 * 2);
    unsigned short* bS   = (unsigned short*)alloc(16384ll * 128 * 2);
    unsigned short* q    = (unsigned short*)alloc(32ll * 512 * 128 * 2);
    unsigned short* k    = (unsigned short*)alloc(32ll * 512 * 128 * 2);
    unsigned short* P     = xn;  // alias: xn dead after UV kernel
    unsigned short* gated = u;   // alias: same-thread read-then-write

    k_convT<<<dim3(100, 24), dim3(32, 8), 0, stream>>>(uv_W, uvWT, 768, 3200);
    k_convT<<<dim3(24, 48), dim3(32, 8), 0, stream>>>(o_W, oWT, 1536, 768);
    k_ln<<<16384, 256, 0, stream>>>(x, ln_g, ln_b, xn);
    // UV merged: u | vT | bS   (N=3328 incl. 128 masked cols; K=768 -> NT=12)
    k8<10, 1, 12><<<dim3(13, 64), 512, 0, stream>>>(
        xn, uvWT, 0, 0, (void*)u, (void*)vT, (void*)bS, (const void*)uv_b);
    k_rope<<<16384, 128, 0, stream>>>(bS, g_qk, b_qk, q, k);
    // QK^T -> P (bz-chunked XCD swizzle inside)
    k_qk<<<dim3(4, 4, 32), 256, 0, stream>>>(q, k, w_rel, P);
    // PV gated by u   (K=512 -> NT=8; flat xyz XCD swizzle)
    k8<2, 2, 8><<<dim3(6, 2, 32), 512, 0, stream>>>(
        P, vT, 512ll * 512, 1536ll * 512, (void*)gated, (void*)u, nullptr, nullptr);
    // out = gated @ oWT^T + o_b + x   (K=1536 -> NT=24)
    k8<3, 1, 24><<<dim3(3, 64), 512, 0, stream>>>(
        gated, oWT, 0, 0, (void*)out, (void*)o_b, (void*)x, nullptr);
}